// Round 2
// baseline (3363.368 us; speedup 1.0000x reference)
//
#include <hip/hip_runtime.h>
#include <math.h>

typedef unsigned int u32;

__device__ __forceinline__ float sigf(float x) { return 1.0f / (1.0f + expf(-x)); }

// =====================================================================
// K1: embedding gather + 1D conv (fs=3,4,5) + ReLU + max-pool over positions
// one block per utterance (u = b*64 + t), 384 threads (6 waves, fs-pure:
// waves 0-1 -> fs3, 2-3 -> fs4, 4-5 -> fs5; lanes = filters).
// Register blocking: each thread keeps ALL P=48-FS+1 position accumulators,
// so each embedding channel e costs 12 broadcast ds_read_b128 + P*FS FMAs
// and each weight row is traversed exactly once.
// =====================================================================
template<int FS>
__device__ __forceinline__ float conv_feat(const float* __restrict__ wrow, float bias,
                                           const float* __restrict__ xs) {
    constexpr int P = 48 - FS + 1;
    float acc[P];
#pragma unroll
    for (int p = 0; p < P; ++p) acc[p] = 0.0f;
    for (int e = 0; e < 300; ++e) {
        float xv[48];
        const float* xr = xs + e * 52;
#pragma unroll
        for (int i = 0; i < 12; ++i)
            *(float4*)&xv[i * 4] = *(const float4*)(xr + i * 4);   // broadcast, 16B aligned
        float wv[FS];
#pragma unroll
        for (int k = 0; k < FS; ++k) wv[k] = wrow[e * FS + k];
#pragma unroll
        for (int k = 0; k < FS; ++k)
#pragma unroll
            for (int p = 0; p < P; ++p)
                acc[p] = fmaf(wv[k], xv[p + k], acc[p]);
    }
    float best = 0.0f;                       // relu(max_p(acc+bias)) == max(0, max_p(...))
#pragma unroll
    for (int p = 0; p < P; ++p) best = fmaxf(best, acc[p] + bias);
    return best;
}

__global__ __launch_bounds__(384) void k_conv(const int* __restrict__ dlg,
                                              const float* __restrict__ emb,
                                              const float* __restrict__ w3, const float* __restrict__ b3,
                                              const float* __restrict__ w4, const float* __restrict__ b4,
                                              const float* __restrict__ w5, const float* __restrict__ b5,
                                              float* __restrict__ feat) {
    __shared__ float xs[300 * 52];   // [e][l], stride 52: 16B-aligned rows, 8-way write conflict (~1% cost)
    __shared__ int   toks[48];
    const int u   = blockIdx.x;
    const int tid = threadIdx.x;
    if (tid < 48) toks[tid] = dlg[u * 48 + tid];
    __syncthreads();
    // gather: consecutive lanes -> consecutive e of one emb row (coalesced global)
    for (int i = tid; i < 300 * 48; i += 384) {
        int l = i / 300;
        int e = i - l * 300;
        xs[e * 52 + l] = emb[(size_t)toks[l] * 300 + e];
    }
    __syncthreads();
    const int grp = tid >> 7;
    const int n   = tid & 127;
    if (n < 100) {
        float r;
        if (grp == 0)      r = conv_feat<3>(w3 + n * 900,  b3[n], xs);
        else if (grp == 1) r = conv_feat<4>(w4 + n * 1200, b4[n], xs);
        else               r = conv_feat<5>(w5 + n * 1500, b5[n], xs);
        feat[(size_t)u * 300 + grp * 100 + n] = r;
    }
}

// =====================================================================
// K2: xg[dir][t][b][g] = feat[b*64+t] . w_ih[g] + (b_ih[g]+b_hh[g])
// grid 512 = 2 dirs x 64 t x 4 g-chunks; 256 threads = 256 g's, 32 b-accumulators
// =====================================================================
__global__ __launch_bounds__(256) void k_xg(const float* __restrict__ feat,
                                            const float* __restrict__ wih_f, const float* __restrict__ bih_f,
                                            const float* __restrict__ bhh_f,
                                            const float* __restrict__ wih_r, const float* __restrict__ bih_r,
                                            const float* __restrict__ bhh_r,
                                            float* __restrict__ xg) {
    __shared__ float fls[300 * 36];   // [d][b], stride 36 keeps float4 alignment
    const int bx  = blockIdx.x;
    const int dir = bx >> 8;
    const int t   = (bx >> 2) & 63;
    const int gc  = bx & 3;
    const int tid = threadIdx.x;
    for (int i = tid; i < 32 * 300; i += 256) {
        int b = i / 300;
        int d = i - b * 300;
        fls[d * 36 + b] = feat[((size_t)b * 64 + t) * 300 + d];
    }
    __syncthreads();
    const int g = gc * 256 + tid;
    const float* wih = dir ? wih_r : wih_f;
    const float* bih = dir ? bih_r : bih_f;
    const float* bhh = dir ? bhh_r : bhh_f;
    const float* wr  = wih + (size_t)g * 300;
    const float bias = bih[g] + bhh[g];
    float acc[32];
#pragma unroll
    for (int b = 0; b < 32; ++b) acc[b] = 0.0f;
    for (int d = 0; d < 300; d += 4) {
        float4 wv = *(const float4*)(wr + d);    // g*300 floats = 1200B: 16B aligned
#pragma unroll
        for (int j = 0; j < 4; ++j) {
            float w = (j == 0) ? wv.x : (j == 1) ? wv.y : (j == 2) ? wv.z : wv.w;
            const float* r = &fls[(d + j) * 36];
#pragma unroll
            for (int bq = 0; bq < 8; ++bq) {
                float4 x = *(const float4*)(r + bq * 4);
                acc[bq * 4 + 0] = fmaf(w, x.x, acc[bq * 4 + 0]);
                acc[bq * 4 + 1] = fmaf(w, x.y, acc[bq * 4 + 1]);
                acc[bq * 4 + 2] = fmaf(w, x.z, acc[bq * 4 + 2]);
                acc[bq * 4 + 3] = fmaf(w, x.w, acc[bq * 4 + 3]);
            }
        }
    }
    float* xo = xg + (((size_t)dir * 64 + t) * 32) * 1024;
#pragma unroll
    for (int b = 0; b < 32; ++b) xo[(size_t)b * 1024 + g] = acc[b] + bias;
}

// =====================================================================
// K3: LSTM recurrence. grid 64 = 2 dirs x 32 batch rows; 256 threads = hidden j.
// thread j owns gate rows {j, 256+j, 512+j, 768+j} (torch order i,f,g,o); h in LDS.
// =====================================================================
__global__ __launch_bounds__(256) void k_lstm(const float* __restrict__ whh_f,
                                              const float* __restrict__ whh_r,
                                              const float* __restrict__ xg,
                                              float* __restrict__ hseq) {
    const int dir = blockIdx.x >> 5;
    const int b   = blockIdx.x & 31;
    const int tid = threadIdx.x;
    const float* whh = dir ? whh_r : whh_f;
    const float* xgd = xg + (size_t)dir * 64 * 32 * 1024;
    float* hout = hseq + (size_t)dir * 64 * 32 * 256;
    __shared__ float hbuf[256];
    hbuf[tid] = 0.0f;
    float cc = 0.0f;
    const float* w0p = whh + (size_t)tid * 256;
    const float* w1p = whh + (size_t)(256 + tid) * 256;
    const float* w2p = whh + (size_t)(512 + tid) * 256;
    const float* w3p = whh + (size_t)(768 + tid) * 256;
    __syncthreads();
    for (int s = 0; s < 64; ++s) {
        const int t = dir ? (63 - s) : s;
        const float* xr = xgd + ((size_t)t * 32 + b) * 1024;
        float ai = xr[tid], af = xr[256 + tid], ag = xr[512 + tid], ao = xr[768 + tid];
#pragma unroll 4
        for (int h0 = 0; h0 < 256; h0 += 4) {
            float4 hv = *(const float4*)&hbuf[h0];
            float4 qa = *(const float4*)(w0p + h0);
            float4 qb = *(const float4*)(w1p + h0);
            float4 qc = *(const float4*)(w2p + h0);
            float4 qd = *(const float4*)(w3p + h0);
            ai = fmaf(qa.x, hv.x, ai); ai = fmaf(qa.y, hv.y, ai);
            ai = fmaf(qa.z, hv.z, ai); ai = fmaf(qa.w, hv.w, ai);
            af = fmaf(qb.x, hv.x, af); af = fmaf(qb.y, hv.y, af);
            af = fmaf(qb.z, hv.z, af); af = fmaf(qb.w, hv.w, af);
            ag = fmaf(qc.x, hv.x, ag); ag = fmaf(qc.y, hv.y, ag);
            ag = fmaf(qc.z, hv.z, ag); ag = fmaf(qc.w, hv.w, ag);
            ao = fmaf(qd.x, hv.x, ao); ao = fmaf(qd.y, hv.y, ao);
            ao = fmaf(qd.z, hv.z, ao); ao = fmaf(qd.w, hv.w, ao);
        }
        float i_ = sigf(ai), f_ = sigf(af), g_ = tanhf(ag), o_ = sigf(ao);
        cc = f_ * cc + i_ * g_;
        float hh = o_ * tanhf(cc);
        __syncthreads();               // all reads of old h done
        hbuf[tid] = hh;
        hout[((size_t)t * 32 + b) * 256 + tid] = hh;
        __syncthreads();               // new h visible
    }
}

// =====================================================================
// K4: head: out[b][t][o] = sigmoid([hf,hr] . head_w[o] + head_b[o])
// =====================================================================
__global__ __launch_bounds__(256) void k_head(const float* __restrict__ hseq,
                                              const float* __restrict__ hw,
                                              const float* __restrict__ hb,
                                              float* __restrict__ out) {
    const int id = blockIdx.x * 256 + threadIdx.x;   // 65536 outputs
    const int o  = id & 31;
    const int u  = id >> 5;          // b*64 + t
    const int b  = u >> 6, t = u & 63;
    const float* pf = hseq + ((size_t)t * 32 + b) * 256;
    const float* pr = hseq + (size_t)64 * 32 * 256 + ((size_t)t * 32 + b) * 256;
    const float* wo = hw + (size_t)o * 512;
    float acc = hb[o];
    for (int j = 0; j < 256; j += 4) {
        float4 wa = *(const float4*)(wo + j);
        float4 wb = *(const float4*)(wo + 256 + j);
        float4 fa = *(const float4*)(pf + j);
        float4 fb = *(const float4*)(pr + j);
        acc = fmaf(wa.x, fa.x, acc); acc = fmaf(wa.y, fa.y, acc);
        acc = fmaf(wa.z, fa.z, acc); acc = fmaf(wa.w, fa.w, acc);
        acc = fmaf(wb.x, fb.x, acc); acc = fmaf(wb.y, fb.y, acc);
        acc = fmaf(wb.z, fb.z, acc); acc = fmaf(wb.w, fb.w, acc);
    }
    out[id] = sigf(acc);
}

// =====================================================================
extern "C" void kernel_launch(void* const* d_in, const int* in_sizes, int n_in,
                              void* d_out, int out_size, void* d_ws, size_t ws_size,
                              hipStream_t stream) {
    const int*   dlg   = (const int*)d_in[0];
    const float* emb   = (const float*)d_in[1];
    const float* w3    = (const float*)d_in[2];  const float* b3    = (const float*)d_in[3];
    const float* w4    = (const float*)d_in[4];  const float* b4    = (const float*)d_in[5];
    const float* w5    = (const float*)d_in[6];  const float* b5    = (const float*)d_in[7];
    const float* wih_f = (const float*)d_in[8];  const float* whh_f = (const float*)d_in[9];
    const float* bih_f = (const float*)d_in[10]; const float* bhh_f = (const float*)d_in[11];
    const float* wih_r = (const float*)d_in[12]; const float* whh_r = (const float*)d_in[13];
    const float* bih_r = (const float*)d_in[14]; const float* bhh_r = (const float*)d_in[15];
    const float* hw    = (const float*)d_in[16]; const float* hb    = (const float*)d_in[17];
    float* out = (float*)d_out;

    float* feat  = (float*)d_ws;            // [2048][300]            = 614400 f
    float* xgbuf = feat + 614400;           // [2][64][32][1024]      = 4194304 f
    float* hseq  = xgbuf + 4194304;         // [2][64][32][256]       = 1048576 f
    // total ~23.4 MB of d_ws

    hipLaunchKernelGGL(k_conv, dim3(2048), dim3(384), 0, stream,
                       dlg, emb, w3, b3, w4, b4, w5, b5, feat);
    hipLaunchKernelGGL(k_xg, dim3(512), dim3(256), 0, stream,
                       feat, wih_f, bih_f, bhh_f, wih_r, bih_r, bhh_r, xgbuf);
    hipLaunchKernelGGL(k_lstm, dim3(64), dim3(256), 0, stream,
                       whh_f, whh_r, xgbuf, hseq);
    hipLaunchKernelGGL(k_head, dim3(256), dim3(256), 0, stream,
                       hseq, hw, hb, out);
}

// Round 3
// 1996.743 us; speedup vs baseline: 1.6844x; 1.6844x over previous
//
#include <hip/hip_runtime.h>
#include <math.h>

typedef unsigned short u16;
typedef unsigned int   u32;

__device__ __forceinline__ float sigf(float x) { return 1.0f / (1.0f + expf(-x)); }
__device__ __forceinline__ u16 f2bf(float f) {
    u32 x = __float_as_uint(f);
    u32 r = (x + 0x7fffu + ((x >> 16) & 1u)) >> 16;   // RNE
    return (u16)r;
}

// =====================================================================
// K1: embedding gather + 1D conv (fs=3,4,5) + ReLU + max-pool over positions
// one block per utterance (u = b*64 + t), 384 threads (6 waves, fs-pure).
// =====================================================================
template<int FS>
__device__ __forceinline__ float conv_feat(const float* __restrict__ wrow, float bias,
                                           const float* __restrict__ xs) {
    constexpr int P = 48 - FS + 1;
    float acc[P];
#pragma unroll
    for (int p = 0; p < P; ++p) acc[p] = 0.0f;
    for (int e = 0; e < 300; ++e) {
        float xv[48];
        const float* xr = xs + e * 52;
#pragma unroll
        for (int i = 0; i < 12; ++i)
            *(float4*)&xv[i * 4] = *(const float4*)(xr + i * 4);   // broadcast, 16B aligned
        float wv[FS];
#pragma unroll
        for (int k = 0; k < FS; ++k) wv[k] = wrow[e * FS + k];
#pragma unroll
        for (int k = 0; k < FS; ++k)
#pragma unroll
            for (int p = 0; p < P; ++p)
                acc[p] = fmaf(wv[k], xv[p + k], acc[p]);
    }
    float best = 0.0f;
#pragma unroll
    for (int p = 0; p < P; ++p) best = fmaxf(best, acc[p] + bias);
    return best;
}

__global__ __launch_bounds__(384) void k_conv(const int* __restrict__ dlg,
                                              const float* __restrict__ emb,
                                              const float* __restrict__ w3, const float* __restrict__ b3,
                                              const float* __restrict__ w4, const float* __restrict__ b4,
                                              const float* __restrict__ w5, const float* __restrict__ b5,
                                              float* __restrict__ feat) {
    __shared__ float xs[300 * 52];
    __shared__ int   toks[48];
    const int u   = blockIdx.x;
    const int tid = threadIdx.x;
    if (tid < 48) toks[tid] = dlg[u * 48 + tid];
    __syncthreads();
    for (int i = tid; i < 300 * 48; i += 384) {
        int l = i / 300;
        int e = i - l * 300;
        xs[e * 52 + l] = emb[(size_t)toks[l] * 300 + e];
    }
    __syncthreads();
    const int grp = tid >> 7;
    const int n   = tid & 127;
    if (n < 100) {
        float r;
        if (grp == 0)      r = conv_feat<3>(w3 + n * 900,  b3[n], xs);
        else if (grp == 1) r = conv_feat<4>(w4 + n * 1200, b4[n], xs);
        else               r = conv_feat<5>(w5 + n * 1500, b5[n], xs);
        feat[(size_t)u * 300 + grp * 100 + n] = r;
    }
}

// =====================================================================
// K2: xg[dir][t][b][g] = feat[b*64+t] . w_ih[g] + (b_ih[g]+b_hh[g])
// =====================================================================
__global__ __launch_bounds__(256) void k_xg(const float* __restrict__ feat,
                                            const float* __restrict__ wih_f, const float* __restrict__ bih_f,
                                            const float* __restrict__ bhh_f,
                                            const float* __restrict__ wih_r, const float* __restrict__ bih_r,
                                            const float* __restrict__ bhh_r,
                                            float* __restrict__ xg) {
    __shared__ float fls[300 * 36];
    const int bx  = blockIdx.x;
    const int dir = bx >> 8;
    const int t   = (bx >> 2) & 63;
    const int gc  = bx & 3;
    const int tid = threadIdx.x;
    for (int i = tid; i < 32 * 300; i += 256) {
        int b = i / 300;
        int d = i - b * 300;
        fls[d * 36 + b] = feat[((size_t)b * 64 + t) * 300 + d];
    }
    __syncthreads();
    const int g = gc * 256 + tid;
    const float* wih = dir ? wih_r : wih_f;
    const float* bih = dir ? bih_r : bih_f;
    const float* bhh = dir ? bhh_r : bhh_f;
    const float* wr  = wih + (size_t)g * 300;
    const float bias = bih[g] + bhh[g];
    float acc[32];
#pragma unroll
    for (int b = 0; b < 32; ++b) acc[b] = 0.0f;
    for (int d = 0; d < 300; d += 4) {
        float4 wv = *(const float4*)(wr + d);
#pragma unroll
        for (int j = 0; j < 4; ++j) {
            float w = (j == 0) ? wv.x : (j == 1) ? wv.y : (j == 2) ? wv.z : wv.w;
            const float* r = &fls[(d + j) * 36];
#pragma unroll
            for (int bq = 0; bq < 8; ++bq) {
                float4 x = *(const float4*)(r + bq * 4);
                acc[bq * 4 + 0] = fmaf(w, x.x, acc[bq * 4 + 0]);
                acc[bq * 4 + 1] = fmaf(w, x.y, acc[bq * 4 + 1]);
                acc[bq * 4 + 2] = fmaf(w, x.z, acc[bq * 4 + 2]);
                acc[bq * 4 + 3] = fmaf(w, x.w, acc[bq * 4 + 3]);
            }
        }
    }
    float* xo = xg + (((size_t)dir * 64 + t) * 32) * 1024;
#pragma unroll
    for (int b = 0; b < 32; ++b) xo[(size_t)b * 1024 + g] = acc[b] + bias;
}

// =====================================================================
// K_prep: transpose w_hh [1024 g][256 k] fp32 -> k-major bf16-packed:
// wt[(dir*64 + k4)*1024 + g] = uint2{ bf(w[g][4k4])|bf(w[g][4k4+1])<<16,
//                                     bf(w[g][4k4+2])|bf(w[g][4k4+3])<<16 }
// lanes (consecutive g) then read consecutive 8B -> 512B/instr coalesced.
// =====================================================================
__global__ __launch_bounds__(256) void k_prep(const float* __restrict__ whh_f,
                                              const float* __restrict__ whh_r,
                                              uint2* __restrict__ wt) {
    const int idx = blockIdx.x * 256 + threadIdx.x;   // 2*64*1024 = 131072
    const int g   = idx & 1023;
    const int k4  = (idx >> 10) & 63;
    const int dir = idx >> 16;
    const float* w = dir ? whh_r : whh_f;
    float4 v = *(const float4*)(w + (size_t)g * 256 + k4 * 4);   // rows 1KB -> 16B aligned
    uint2 o;
    o.x = (u32)f2bf(v.x) | ((u32)f2bf(v.y) << 16);
    o.y = (u32)f2bf(v.z) | ((u32)f2bf(v.w) << 16);
    wt[idx] = o;
}

// =====================================================================
// K3: LSTM recurrence. grid 64 = 2 dirs x 32 batch rows; 256 threads = hidden j.
// Weights: k-major bf16 (L2-resident, 512KB/dir/step), coalesced across lanes.
// h kept fp32 in LDS; fp32 accumulate; torch gate order i,f,g,o.
// =====================================================================
__global__ __launch_bounds__(256) void k_lstm(const uint2* __restrict__ wt,
                                              const float* __restrict__ xg,
                                              float* __restrict__ hseq) {
    const int dir = blockIdx.x >> 5;
    const int b   = blockIdx.x & 31;
    const int tid = threadIdx.x;
    const float* xgd = xg + (size_t)dir * 64 * 32 * 1024;
    float* hout = hseq + (size_t)dir * 64 * 32 * 256;
    const uint2* wbase = wt + (size_t)dir * 65536 + tid;
    __shared__ float hbuf[256];
    hbuf[tid] = 0.0f;
    float cc = 0.0f;
    __syncthreads();
    for (int s = 0; s < 64; ++s) {
        const int t = dir ? (63 - s) : s;
        const float* xr = xgd + ((size_t)t * 32 + b) * 1024;
        float ai = xr[tid], af = xr[256 + tid], ag = xr[512 + tid], ao = xr[768 + tid];
#pragma unroll 8
        for (int k4 = 0; k4 < 64; ++k4) {
            uint2 q0 = wbase[k4 * 1024];
            uint2 q1 = wbase[k4 * 1024 + 256];
            uint2 q2 = wbase[k4 * 1024 + 512];
            uint2 q3 = wbase[k4 * 1024 + 768];
            float4 hv = *(const float4*)&hbuf[k4 * 4];   // broadcast b128
#define G4(acc, q)                                                          \
            acc = fmaf(__uint_as_float((q).x << 16),         hv.x, acc);    \
            acc = fmaf(__uint_as_float((q).x & 0xffff0000u), hv.y, acc);    \
            acc = fmaf(__uint_as_float((q).y << 16),         hv.z, acc);    \
            acc = fmaf(__uint_as_float((q).y & 0xffff0000u), hv.w, acc);
            G4(ai, q0)
            G4(af, q1)
            G4(ag, q2)
            G4(ao, q3)
#undef G4
        }
        float i_ = sigf(ai), f_ = sigf(af), g_ = tanhf(ag), o_ = sigf(ao);
        cc = f_ * cc + i_ * g_;
        float hh = o_ * tanhf(cc);
        __syncthreads();               // all reads of old h done
        hbuf[tid] = hh;
        hout[((size_t)t * 32 + b) * 256 + tid] = hh;
        __syncthreads();               // new h visible
    }
}

// =====================================================================
// K4: head
// =====================================================================
__global__ __launch_bounds__(256) void k_head(const float* __restrict__ hseq,
                                              const float* __restrict__ hw,
                                              const float* __restrict__ hb,
                                              float* __restrict__ out) {
    const int id = blockIdx.x * 256 + threadIdx.x;
    const int o  = id & 31;
    const int u  = id >> 5;
    const int b  = u >> 6, t = u & 63;
    const float* pf = hseq + ((size_t)t * 32 + b) * 256;
    const float* pr = hseq + (size_t)64 * 32 * 256 + ((size_t)t * 32 + b) * 256;
    const float* wo = hw + (size_t)o * 512;
    float acc = hb[o];
    for (int j = 0; j < 256; j += 4) {
        float4 wa = *(const float4*)(wo + j);
        float4 wb = *(const float4*)(wo + 256 + j);
        float4 fa = *(const float4*)(pf + j);
        float4 fb = *(const float4*)(pr + j);
        acc = fmaf(wa.x, fa.x, acc); acc = fmaf(wa.y, fa.y, acc);
        acc = fmaf(wa.z, fa.z, acc); acc = fmaf(wa.w, fa.w, acc);
        acc = fmaf(wb.x, fb.x, acc); acc = fmaf(wb.y, fb.y, acc);
        acc = fmaf(wb.z, fb.z, acc); acc = fmaf(wb.w, fb.w, acc);
    }
    out[id] = sigf(acc);
}

// =====================================================================
extern "C" void kernel_launch(void* const* d_in, const int* in_sizes, int n_in,
                              void* d_out, int out_size, void* d_ws, size_t ws_size,
                              hipStream_t stream) {
    const int*   dlg   = (const int*)d_in[0];
    const float* emb   = (const float*)d_in[1];
    const float* w3    = (const float*)d_in[2];  const float* b3    = (const float*)d_in[3];
    const float* w4    = (const float*)d_in[4];  const float* b4    = (const float*)d_in[5];
    const float* w5    = (const float*)d_in[6];  const float* b5    = (const float*)d_in[7];
    const float* wih_f = (const float*)d_in[8];  const float* whh_f = (const float*)d_in[9];
    const float* bih_f = (const float*)d_in[10]; const float* bhh_f = (const float*)d_in[11];
    const float* wih_r = (const float*)d_in[12]; const float* whh_r = (const float*)d_in[13];
    const float* bih_r = (const float*)d_in[14]; const float* bhh_r = (const float*)d_in[15];
    const float* hw    = (const float*)d_in[16]; const float* hb    = (const float*)d_in[17];
    float* out = (float*)d_out;

    float* feat  = (float*)d_ws;            // [2048][300]            = 614400 f
    float* xgbuf = feat + 614400;           // [2][64][32][1024]      = 4194304 f
    float* hseq  = xgbuf + 4194304;         // [2][64][32][256]       = 1048576 f
    uint2* wt    = (uint2*)(hseq + 1048576);// [2][64][1024] uint2    = 1 MB
    // total ~24.4 MB of d_ws

    hipLaunchKernelGGL(k_prep, dim3(512), dim3(256), 0, stream,
                       whh_f, whh_r, wt);
    hipLaunchKernelGGL(k_conv, dim3(2048), dim3(384), 0, stream,
                       dlg, emb, w3, b3, w4, b4, w5, b5, feat);
    hipLaunchKernelGGL(k_xg, dim3(512), dim3(256), 0, stream,
                       feat, wih_f, bih_f, bhh_f, wih_r, bih_r, bhh_r, xgbuf);
    hipLaunchKernelGGL(k_lstm, dim3(64), dim3(256), 0, stream,
                       wt, xgbuf, hseq);
    hipLaunchKernelGGL(k_head, dim3(256), dim3(256), 0, stream,
                       hseq, hw, hb, out);
}

// Round 4
// 974.366 us; speedup vs baseline: 3.4519x; 2.0493x over previous
//
#include <hip/hip_runtime.h>
#include <math.h>

typedef unsigned short u16;
typedef unsigned int   u32;
typedef float  v16f __attribute__((ext_vector_type(16)));
typedef short  v8s  __attribute__((ext_vector_type(8)));

__device__ __forceinline__ float sigf(float x) { return 1.0f / (1.0f + expf(-x)); }
__device__ __forceinline__ u16 f2bf(float f) {
    u32 x = __float_as_uint(f);
    u32 r = (x + 0x7fffu + ((x >> 16) & 1u)) >> 16;   // RNE
    return (u16)r;
}

// ---------------------------------------------------------------------
// Conv-as-MFMA constants:
//   per fs-group g (fs=3,4,5): C[p][f] = sum_kk sum_e X[p+kk][e] * W_kk[e][f]
//   K per MFMA = 16 e's; e padded 300->304 => KE=19 e-steps; filters padded
//   100->128 => 4 n-tiles of 32. M = 2 utts * 48 positions = 96 = 3 m-tiles.
// Weight repack layout (bf16), B-fragment order:
//   wkr[g][kk][ke][f(128)][q(2)][j(8)],  value = w_g[f][e=ke*16+q*8+j][kk]
//   slab stride per (kk,ke) = 128*16 = 2048 elts (4 KB)
// group offsets in elts: g0=0, g1=3*19*2048, g2=(3+4)*19*2048
// ---------------------------------------------------------------------
#define KE        19
#define SLAB      2048
#define G0_OFF    0
#define G1_OFF    (3 * KE * SLAB)
#define G2_OFF    (7 * KE * SLAB)
#define WKR_TOT   (12 * KE * SLAB)     // 466944 elts
#define XSTR      312                  // xT row stride (elts); 624B, 16B-aligned

__global__ __launch_bounds__(256) void k_cprep(const float* __restrict__ w3,
                                               const float* __restrict__ w4,
                                               const float* __restrict__ w5,
                                               u16* __restrict__ wkr) {
    const int gid = blockIdx.x * 256 + threadIdx.x;    // [0, 466944)
    int g, rem;
    if (gid < G1_OFF)      { g = 0; rem = gid; }
    else if (gid < G2_OFF) { g = 1; rem = gid - G1_OFF; }
    else                   { g = 2; rem = gid - G2_OFF; }
    const int fs = 3 + g;
    const int j  = rem & 7;
    const int q  = (rem >> 3) & 1;
    const int f  = (rem >> 4) & 127;
    const int t  = rem >> 11;          // [0, fs*19)
    const int ke = t % KE;
    const int kk = t / KE;
    const int e  = ke * 16 + q * 8 + j;
    float v = 0.0f;
    if (f < 100 && e < 300) {
        const float* w = (g == 0) ? w3 : (g == 1) ? w4 : w5;
        v = w[((size_t)f * 300 + e) * fs + kk];
    }
    wkr[gid] = f2bf(v);
}

// =====================================================================
// K1: conv via MFMA. 1024 blocks (2 utts each), 384 threads (6 waves).
// LDS: xT[104][312] bf16 (2 utt x 52-row slots; rows 48..51 zero pad).
// waves 0..3: (g0, nt=wv) + (g2, nt=wv);  waves 4,5: g1 nt pairs.
// 456 MFMAs/wave, A-frags shared across groups, B-frags across m-tiles.
// =====================================================================
__global__ __launch_bounds__(384) void k_conv_mfma(const int* __restrict__ dlg,
                                                   const float* __restrict__ emb,
                                                   const u16* __restrict__ wkr,
                                                   const float* __restrict__ b3,
                                                   const float* __restrict__ b4,
                                                   const float* __restrict__ b5,
                                                   float* __restrict__ feat) {
    __shared__ u16 xT[104 * XSTR];     // 64896 B
    __shared__ int toks[96];
    const int u2  = blockIdx.x;
    const int tid = threadIdx.x;
    if (tid < 96) toks[tid] = dlg[u2 * 96 + tid];
    __syncthreads();
    // stage x as bf16: 96 tokens x 75 float4 e-chunks
    for (int i = tid; i < 96 * 75; i += 384) {
        int t  = i / 75;
        int e4 = i - t * 75;
        int utt = (t >= 48);
        int row = utt * 52 + (t - utt * 48);
        float4 v = *(const float4*)(emb + (size_t)toks[t] * 300 + e4 * 4);
        uint2 o;
        o.x = (u32)f2bf(v.x) | ((u32)f2bf(v.y) << 16);
        o.y = (u32)f2bf(v.z) | ((u32)f2bf(v.w) << 16);
        *(uint2*)&xT[row * XSTR + e4 * 4] = o;
    }
    // zero pad rows 48..51 and 100..103 (read via kk-shift, masked in epilogue)
    for (int i = tid; i < 8 * (XSTR / 2); i += 384) {
        int r = i / (XSTR / 2);
        int c = i - r * (XSTR / 2);
        int row = (r < 4) ? (48 + r) : (96 + r - 4);
        *(u32*)&xT[row * XSTR + c * 2] = 0;
    }
    __syncthreads();

    const int wv   = tid >> 6;
    const int lane = tid & 63;
    const int m    = lane & 31;
    const int q    = lane >> 5;

    // per-lane A base (elts) for 3 m-tiles: row r = mt*32+m -> (utt, p)
    int abase[3];
#pragma unroll
    for (int mt = 0; mt < 3; ++mt) {
        int r = mt * 32 + m;
        int utt = (r >= 48);
        int p = r - utt * 48;
        abase[mt] = (utt * 52 + p) * XSTR + q * 8;
    }

    // wave assignment
    int gA, ntA, gB, ntB, kkA, kkB;
    if (wv < 4) { gA = 0; ntA = wv; gB = 2; ntB = wv; kkA = 3; kkB = 5; }
    else        { gA = 1; ntA = (wv - 4) * 2; gB = 1; ntB = ntA + 1; kkA = 4; kkB = 4; }
    const int kkmax = (kkA > kkB) ? kkA : kkB;
    const int goffA = (gA == 0) ? G0_OFF : (gA == 1) ? G1_OFF : G2_OFF;
    const int goffB = (gB == 0) ? G0_OFF : (gB == 1) ? G1_OFF : G2_OFF;
    const int laneoffA = ((ntA * 32 + m) * 2 + q) * 8;
    const int laneoffB = ((ntB * 32 + m) * 2 + q) * 8;
    const u16* wA = wkr + goffA + laneoffA;
    const u16* wB = wkr + goffB + laneoffB;

    v16f accA[3], accB[3];
#pragma unroll
    for (int mt = 0; mt < 3; ++mt) {
#pragma unroll
        for (int r = 0; r < 16; ++r) { accA[mt][r] = 0.0f; accB[mt][r] = 0.0f; }
    }

    for (int kk = 0; kk < kkmax; ++kk) {
        const bool doA = (kk < kkA);
        const bool doB = (kk < kkB);
        const int xshift = kk * XSTR;
        for (int ke = 0; ke < KE; ++ke) {
            v8s bfA, bfB;
            if (doA) bfA = *(const v8s*)(wA + (kk * KE + ke) * SLAB);
            if (doB) bfB = *(const v8s*)(wB + (kk * KE + ke) * SLAB);
            const int xcol = ke * 16;
#pragma unroll
            for (int mt = 0; mt < 3; ++mt) {
                v8s af = *(const v8s*)&xT[abase[mt] + xshift + xcol];
                if (doA) accA[mt] = __builtin_amdgcn_mfma_f32_32x32x16_bf16(af, bfA, accA[mt], 0, 0, 0);
                if (doB) accB[mt] = __builtin_amdgcn_mfma_f32_32x32x16_bf16(af, bfB, accB[mt], 0, 0, 0);
            }
        }
    }

    // epilogue: bias + relu + maxpool over valid p, per (group, nt) tile
    const int PP[3] = {46, 45, 44};
#pragma unroll
    for (int which = 0; which < 2; ++which) {
        const int g  = which ? gB : gA;
        const int nt = which ? ntB : ntA;
        const v16f* acc = which ? accB : accA;
        const float* bg = (g == 0) ? b3 : (g == 1) ? b4 : b5;
        const int f = nt * 32 + m;
        const float bias = (f < 100) ? bg[f] : 0.0f;
        const int Pg = PP[g];
        float v0 = -1e30f, v1 = -1e30f;
#pragma unroll
        for (int mt = 0; mt < 3; ++mt) {
#pragma unroll
            for (int reg = 0; reg < 16; ++reg) {
                int row = (reg & 3) + 8 * (reg >> 2) + 4 * q;
                int r = mt * 32 + row;
                int utt = (r >= 48);
                int p = r - utt * 48;
                if (p < Pg) {
                    float val = acc[mt][reg] + bias;
                    if (utt) v1 = fmaxf(v1, val); else v0 = fmaxf(v0, val);
                }
            }
        }
        v0 = fmaxf(v0, __shfl_xor(v0, 32, 64));
        v1 = fmaxf(v1, __shfl_xor(v1, 32, 64));
        if (q == 0 && f < 100) {
            feat[((size_t)(u2 * 2 + 0)) * 300 + g * 100 + f] = fmaxf(0.0f, v0);
            feat[((size_t)(u2 * 2 + 1)) * 300 + g * 100 + f] = fmaxf(0.0f, v1);
        }
    }
}

// =====================================================================
// K2: xg[dir][t][b][g] = feat[b*64+t] . w_ih[g] + (b_ih[g]+b_hh[g])
// =====================================================================
__global__ __launch_bounds__(256) void k_xg(const float* __restrict__ feat,
                                            const float* __restrict__ wih_f, const float* __restrict__ bih_f,
                                            const float* __restrict__ bhh_f,
                                            const float* __restrict__ wih_r, const float* __restrict__ bih_r,
                                            const float* __restrict__ bhh_r,
                                            float* __restrict__ xg) {
    __shared__ float fls[300 * 36];
    const int bx  = blockIdx.x;
    const int dir = bx >> 8;
    const int t   = (bx >> 2) & 63;
    const int gc  = bx & 3;
    const int tid = threadIdx.x;
    for (int i = tid; i < 32 * 300; i += 256) {
        int b = i / 300;
        int d = i - b * 300;
        fls[d * 36 + b] = feat[((size_t)b * 64 + t) * 300 + d];
    }
    __syncthreads();
    const int g = gc * 256 + tid;
    const float* wih = dir ? wih_r : wih_f;
    const float* bih = dir ? bih_r : bih_f;
    const float* bhh = dir ? bhh_r : bhh_f;
    const float* wr  = wih + (size_t)g * 300;
    const float bias = bih[g] + bhh[g];
    float acc[32];
#pragma unroll
    for (int b = 0; b < 32; ++b) acc[b] = 0.0f;
    for (int d = 0; d < 300; d += 4) {
        float4 wv = *(const float4*)(wr + d);
#pragma unroll
        for (int j = 0; j < 4; ++j) {
            float w = (j == 0) ? wv.x : (j == 1) ? wv.y : (j == 2) ? wv.z : wv.w;
            const float* r = &fls[(d + j) * 36];
#pragma unroll
            for (int bq = 0; bq < 8; ++bq) {
                float4 x = *(const float4*)(r + bq * 4);
                acc[bq * 4 + 0] = fmaf(w, x.x, acc[bq * 4 + 0]);
                acc[bq * 4 + 1] = fmaf(w, x.y, acc[bq * 4 + 1]);
                acc[bq * 4 + 2] = fmaf(w, x.z, acc[bq * 4 + 2]);
                acc[bq * 4 + 3] = fmaf(w, x.w, acc[bq * 4 + 3]);
            }
        }
    }
    float* xo = xg + (((size_t)dir * 64 + t) * 32) * 1024;
#pragma unroll
    for (int b = 0; b < 32; ++b) xo[(size_t)b * 1024 + g] = acc[b] + bias;
}

// =====================================================================
// K_prep: w_hh -> k-major bf16-packed for coalesced lstm reads
// =====================================================================
__global__ __launch_bounds__(256) void k_prep(const float* __restrict__ whh_f,
                                              const float* __restrict__ whh_r,
                                              uint2* __restrict__ wt) {
    const int idx = blockIdx.x * 256 + threadIdx.x;   // 131072
    const int g   = idx & 1023;
    const int k4  = (idx >> 10) & 63;
    const int dir = idx >> 16;
    const float* w = dir ? whh_r : whh_f;
    float4 v = *(const float4*)(w + (size_t)g * 256 + k4 * 4);
    uint2 o;
    o.x = (u32)f2bf(v.x) | ((u32)f2bf(v.y) << 16);
    o.y = (u32)f2bf(v.z) | ((u32)f2bf(v.w) << 16);
    wt[idx] = o;
}

// =====================================================================
// K3: LSTM recurrence. 64 blocks = 2 dirs x 32 batch; 256 threads = hidden j.
// =====================================================================
__global__ __launch_bounds__(256) void k_lstm(const uint2* __restrict__ wt,
                                              const float* __restrict__ xg,
                                              float* __restrict__ hseq) {
    const int dir = blockIdx.x >> 5;
    const int b   = blockIdx.x & 31;
    const int tid = threadIdx.x;
    const float* xgd = xg + (size_t)dir * 64 * 32 * 1024;
    float* hout = hseq + (size_t)dir * 64 * 32 * 256;
    const uint2* wbase = wt + (size_t)dir * 65536 + tid;
    __shared__ float hbuf[256];
    hbuf[tid] = 0.0f;
    float cc = 0.0f;
    __syncthreads();
    for (int s = 0; s < 64; ++s) {
        const int t = dir ? (63 - s) : s;
        const float* xr = xgd + ((size_t)t * 32 + b) * 1024;
        float ai = xr[tid], af = xr[256 + tid], ag = xr[512 + tid], ao = xr[768 + tid];
#pragma unroll 8
        for (int k4 = 0; k4 < 64; ++k4) {
            uint2 q0 = wbase[k4 * 1024];
            uint2 q1 = wbase[k4 * 1024 + 256];
            uint2 q2 = wbase[k4 * 1024 + 512];
            uint2 q3 = wbase[k4 * 1024 + 768];
            float4 hv = *(const float4*)&hbuf[k4 * 4];
#define G4(acc, qq)                                                          \
            acc = fmaf(__uint_as_float((qq).x << 16),         hv.x, acc);    \
            acc = fmaf(__uint_as_float((qq).x & 0xffff0000u), hv.y, acc);    \
            acc = fmaf(__uint_as_float((qq).y << 16),         hv.z, acc);    \
            acc = fmaf(__uint_as_float((qq).y & 0xffff0000u), hv.w, acc);
            G4(ai, q0)
            G4(af, q1)
            G4(ag, q2)
            G4(ao, q3)
#undef G4
        }
        float i_ = sigf(ai), f_ = sigf(af), g_ = tanhf(ag), o_ = sigf(ao);
        cc = f_ * cc + i_ * g_;
        float hh = o_ * tanhf(cc);
        __syncthreads();
        hbuf[tid] = hh;
        hout[((size_t)t * 32 + b) * 256 + tid] = hh;
        __syncthreads();
    }
}

// =====================================================================
// K4: head
// =====================================================================
__global__ __launch_bounds__(256) void k_head(const float* __restrict__ hseq,
                                              const float* __restrict__ hw,
                                              const float* __restrict__ hb,
                                              float* __restrict__ out) {
    const int id = blockIdx.x * 256 + threadIdx.x;
    const int o  = id & 31;
    const int u  = id >> 5;
    const int b  = u >> 6, t = u & 63;
    const float* pf = hseq + ((size_t)t * 32 + b) * 256;
    const float* pr = hseq + (size_t)64 * 32 * 256 + ((size_t)t * 32 + b) * 256;
    const float* wo = hw + (size_t)o * 512;
    float acc = hb[o];
    for (int j = 0; j < 256; j += 4) {
        float4 wa = *(const float4*)(wo + j);
        float4 wb = *(const float4*)(wo + 256 + j);
        float4 fa = *(const float4*)(pf + j);
        float4 fb = *(const float4*)(pr + j);
        acc = fmaf(wa.x, fa.x, acc); acc = fmaf(wa.y, fa.y, acc);
        acc = fmaf(wa.z, fa.z, acc); acc = fmaf(wa.w, fa.w, acc);
        acc = fmaf(wb.x, fb.x, acc); acc = fmaf(wb.y, fb.y, acc);
        acc = fmaf(wb.z, fb.z, acc); acc = fmaf(wb.w, fb.w, acc);
    }
    out[id] = sigf(acc);
}

// =====================================================================
extern "C" void kernel_launch(void* const* d_in, const int* in_sizes, int n_in,
                              void* d_out, int out_size, void* d_ws, size_t ws_size,
                              hipStream_t stream) {
    const int*   dlg   = (const int*)d_in[0];
    const float* emb   = (const float*)d_in[1];
    const float* w3    = (const float*)d_in[2];  const float* b3    = (const float*)d_in[3];
    const float* w4    = (const float*)d_in[4];  const float* b4    = (const float*)d_in[5];
    const float* w5    = (const float*)d_in[6];  const float* b5    = (const float*)d_in[7];
    const float* wih_f = (const float*)d_in[8];  const float* whh_f = (const float*)d_in[9];
    const float* bih_f = (const float*)d_in[10]; const float* bhh_f = (const float*)d_in[11];
    const float* wih_r = (const float*)d_in[12]; const float* whh_r = (const float*)d_in[13];
    const float* bih_r = (const float*)d_in[14]; const float* bhh_r = (const float*)d_in[15];
    const float* hw    = (const float*)d_in[16]; const float* hb    = (const float*)d_in[17];
    float* out = (float*)d_out;

    float* feat  = (float*)d_ws;              // [2048][300]
    float* xgbuf = feat + 614400;             // [2][64][32][1024]
    float* hseq  = xgbuf + 4194304;           // [2][64][32][256]
    uint2* wt    = (uint2*)(hseq + 1048576);  // [2][64][1024] uint2
    u16*   wkr   = (u16*)(wt + 131072);       // 466944 u16 (~0.9 MB)

    hipLaunchKernelGGL(k_cprep, dim3(WKR_TOT / 256), dim3(256), 0, stream,
                       w3, w4, w5, wkr);
    hipLaunchKernelGGL(k_prep, dim3(512), dim3(256), 0, stream,
                       whh_f, whh_r, wt);
    hipLaunchKernelGGL(k_conv_mfma, dim3(1024), dim3(384), 0, stream,
                       dlg, emb, wkr, b3, b4, b5, feat);
    hipLaunchKernelGGL(k_xg, dim3(512), dim3(256), 0, stream,
                       feat, wih_f, bih_f, bhh_f, wih_r, bih_r, bhh_r, xgbuf);
    hipLaunchKernelGGL(k_lstm, dim3(64), dim3(256), 0, stream,
                       wt, xgbuf, hseq);
    hipLaunchKernelGGL(k_head, dim3(256), dim3(256), 0, stream,
                       hseq, hw, hb, out);
}

// Round 6
// 694.115 us; speedup vs baseline: 4.8455x; 1.4038x over previous
//
#include <hip/hip_runtime.h>
#include <math.h>

typedef unsigned short u16;
typedef unsigned int   u32;
typedef float  v16f __attribute__((ext_vector_type(16)));
typedef short  v8s  __attribute__((ext_vector_type(8)));

__device__ __forceinline__ float sigf(float x) { return 1.0f / (1.0f + __expf(-x)); }
__device__ __forceinline__ float tanhfast(float x) { return 2.0f / (1.0f + __expf(-2.0f * x)) - 1.0f; }
__device__ __forceinline__ u16 f2bf(float f) {
    u32 x = __float_as_uint(f);
    u32 r = (x + 0x7fffu + ((x >> 16) & 1u)) >> 16;   // RNE
    return (u16)r;
}

// ---------------------------------------------------------------------
// Conv-as-MFMA constants (verified R4)
// ---------------------------------------------------------------------
#define KE        19
#define SLAB      2048
#define G0_OFF    0
#define G1_OFF    (3 * KE * SLAB)
#define G2_OFF    (7 * KE * SLAB)
#define WKR_TOT   (12 * KE * SLAB)
#define XSTR      312

__global__ __launch_bounds__(256) void k_cprep(const float* __restrict__ w3,
                                               const float* __restrict__ w4,
                                               const float* __restrict__ w5,
                                               u16* __restrict__ wkr) {
    const int gid = blockIdx.x * 256 + threadIdx.x;
    int g, rem;
    if (gid < G1_OFF)      { g = 0; rem = gid; }
    else if (gid < G2_OFF) { g = 1; rem = gid - G1_OFF; }
    else                   { g = 2; rem = gid - G2_OFF; }
    const int fs = 3 + g;
    const int j  = rem & 7;
    const int q  = (rem >> 3) & 1;
    const int f  = (rem >> 4) & 127;
    const int t  = rem >> 11;
    const int ke = t % KE;
    const int kk = t / KE;
    const int e  = ke * 16 + q * 8 + j;
    float v = 0.0f;
    if (f < 100 && e < 300) {
        const float* w = (g == 0) ? w3 : (g == 1) ? w4 : w5;
        v = w[((size_t)f * 300 + e) * fs + kk];
    }
    wkr[gid] = f2bf(v);
}

// =====================================================================
// K1: conv via MFMA (unchanged from R4)
// =====================================================================
__global__ __launch_bounds__(384) void k_conv_mfma(const int* __restrict__ dlg,
                                                   const float* __restrict__ emb,
                                                   const u16* __restrict__ wkr,
                                                   const float* __restrict__ b3,
                                                   const float* __restrict__ b4,
                                                   const float* __restrict__ b5,
                                                   float* __restrict__ feat) {
    __shared__ u16 xT[104 * XSTR];
    __shared__ int toks[96];
    const int u2  = blockIdx.x;
    const int tid = threadIdx.x;
    if (tid < 96) toks[tid] = dlg[u2 * 96 + tid];
    __syncthreads();
    for (int i = tid; i < 96 * 75; i += 384) {
        int t  = i / 75;
        int e4 = i - t * 75;
        int utt = (t >= 48);
        int row = utt * 52 + (t - utt * 48);
        float4 v = *(const float4*)(emb + (size_t)toks[t] * 300 + e4 * 4);
        uint2 o;
        o.x = (u32)f2bf(v.x) | ((u32)f2bf(v.y) << 16);
        o.y = (u32)f2bf(v.z) | ((u32)f2bf(v.w) << 16);
        *(uint2*)&xT[row * XSTR + e4 * 4] = o;
    }
    for (int i = tid; i < 8 * (XSTR / 2); i += 384) {
        int r = i / (XSTR / 2);
        int c = i - r * (XSTR / 2);
        int row = (r < 4) ? (48 + r) : (96 + r - 4);
        *(u32*)&xT[row * XSTR + c * 2] = 0;
    }
    __syncthreads();

    const int wv   = tid >> 6;
    const int lane = tid & 63;
    const int m    = lane & 31;
    const int q    = lane >> 5;

    int abase[3];
#pragma unroll
    for (int mt = 0; mt < 3; ++mt) {
        int r = mt * 32 + m;
        int utt = (r >= 48);
        int p = r - utt * 48;
        abase[mt] = (utt * 52 + p) * XSTR + q * 8;
    }

    int gA, ntA, gB, ntB, kkA, kkB;
    if (wv < 4) { gA = 0; ntA = wv; gB = 2; ntB = wv; kkA = 3; kkB = 5; }
    else        { gA = 1; ntA = (wv - 4) * 2; gB = 1; ntB = ntA + 1; kkA = 4; kkB = 4; }
    const int kkmax = (kkA > kkB) ? kkA : kkB;
    const int goffA = (gA == 0) ? G0_OFF : (gA == 1) ? G1_OFF : G2_OFF;
    const int goffB = (gB == 0) ? G0_OFF : (gB == 1) ? G1_OFF : G2_OFF;
    const u16* wA = wkr + goffA + ((ntA * 32 + m) * 2 + q) * 8;
    const u16* wB = wkr + goffB + ((ntB * 32 + m) * 2 + q) * 8;

    v16f accA[3], accB[3];
#pragma unroll
    for (int mt = 0; mt < 3; ++mt) {
#pragma unroll
        for (int r = 0; r < 16; ++r) { accA[mt][r] = 0.0f; accB[mt][r] = 0.0f; }
    }

    for (int kk = 0; kk < kkmax; ++kk) {
        const bool doA = (kk < kkA);
        const bool doB = (kk < kkB);
        const int xshift = kk * XSTR;
        for (int ke = 0; ke < KE; ++ke) {
            v8s bfA, bfB;
            if (doA) bfA = *(const v8s*)(wA + (kk * KE + ke) * SLAB);
            if (doB) bfB = *(const v8s*)(wB + (kk * KE + ke) * SLAB);
            const int xcol = ke * 16;
#pragma unroll
            for (int mt = 0; mt < 3; ++mt) {
                v8s af = *(const v8s*)&xT[abase[mt] + xshift + xcol];
                if (doA) accA[mt] = __builtin_amdgcn_mfma_f32_32x32x16_bf16(af, bfA, accA[mt], 0, 0, 0);
                if (doB) accB[mt] = __builtin_amdgcn_mfma_f32_32x32x16_bf16(af, bfB, accB[mt], 0, 0, 0);
            }
        }
    }

    const int PP[3] = {46, 45, 44};
#pragma unroll
    for (int which = 0; which < 2; ++which) {
        const int g  = which ? gB : gA;
        const int nt = which ? ntB : ntA;
        const v16f* acc = which ? accB : accA;
        const float* bg = (g == 0) ? b3 : (g == 1) ? b4 : b5;
        const int f = nt * 32 + m;
        const float bias = (f < 100) ? bg[f] : 0.0f;
        const int Pg = PP[g];
        float v0 = -1e30f, v1 = -1e30f;
#pragma unroll
        for (int mt = 0; mt < 3; ++mt) {
#pragma unroll
            for (int reg = 0; reg < 16; ++reg) {
                int row = (reg & 3) + 8 * (reg >> 2) + 4 * q;
                int r = mt * 32 + row;
                int utt = (r >= 48);
                int p = r - utt * 48;
                if (p < Pg) {
                    float val = acc[mt][reg] + bias;
                    if (utt) v1 = fmaxf(v1, val); else v0 = fmaxf(v0, val);
                }
            }
        }
        v0 = fmaxf(v0, __shfl_xor(v0, 32, 64));
        v1 = fmaxf(v1, __shfl_xor(v1, 32, 64));
        if (q == 0 && f < 100) {
            feat[((size_t)(u2 * 2 + 0)) * 300 + g * 100 + f] = fmaxf(0.0f, v0);
            feat[((size_t)(u2 * 2 + 1)) * 300 + g * 100 + f] = fmaxf(0.0f, v1);
        }
    }
}

// =====================================================================
// K2: xg GEMM; output written directly in MFMA C-fragment order:
// xgF[dir][t][slot(32)= js*8+nt][reg(16)][lane(64)]  (n_local = jjl*4+gate)
// =====================================================================
__global__ __launch_bounds__(256) void k_xg(const float* __restrict__ feat,
                                            const float* __restrict__ wih_f, const float* __restrict__ bih_f,
                                            const float* __restrict__ bhh_f,
                                            const float* __restrict__ wih_r, const float* __restrict__ bih_r,
                                            const float* __restrict__ bhh_r,
                                            float* __restrict__ xgF) {
    __shared__ float fls[300 * 36];
    const int bx  = blockIdx.x;
    const int dir = bx >> 8;
    const int t   = (bx >> 2) & 63;
    const int gc  = bx & 3;                   // gate index (0..3)
    const int tid = threadIdx.x;
    for (int i = tid; i < 32 * 300; i += 256) {
        int b = i / 300;
        int d = i - b * 300;
        fls[d * 36 + b] = feat[((size_t)b * 64 + t) * 300 + d];
    }
    __syncthreads();
    const int g = gc * 256 + tid;             // global gate-row, gate-major
    const float* wih = dir ? wih_r : wih_f;
    const float* bih = dir ? bih_r : bih_f;
    const float* bhh = dir ? bhh_r : bhh_f;
    const float* wr  = wih + (size_t)g * 300;
    const float bias = bih[g] + bhh[g];
    float acc[32];
#pragma unroll
    for (int b = 0; b < 32; ++b) acc[b] = 0.0f;
    for (int d = 0; d < 300; d += 4) {
        float4 wv = *(const float4*)(wr + d);
#pragma unroll
        for (int j = 0; j < 4; ++j) {
            float w = (j == 0) ? wv.x : (j == 1) ? wv.y : (j == 2) ? wv.z : wv.w;
            const float* r = &fls[(d + j) * 36];
#pragma unroll
            for (int bq = 0; bq < 8; ++bq) {
                float4 x = *(const float4*)(r + bq * 4);
                acc[bq * 4 + 0] = fmaf(w, x.x, acc[bq * 4 + 0]);
                acc[bq * 4 + 1] = fmaf(w, x.y, acc[bq * 4 + 1]);
                acc[bq * 4 + 2] = fmaf(w, x.z, acc[bq * 4 + 2]);
                acc[bq * 4 + 3] = fmaf(w, x.w, acc[bq * 4 + 3]);
            }
        }
    }
    // scatter to C-fragment layout
    const int jj      = tid;                  // hidden unit 0..255
    const int js      = jj >> 6;
    const int n_local = ((jj & 63) << 2) | gc;
    const int nt      = n_local >> 5;
    const int lane_lo = n_local & 31;
    float* base = xgF + (((size_t)(dir * 64 + t) * 32) + js * 8 + nt) * 1024;
#pragma unroll
    for (int b = 0; b < 32; ++b) {
        int q    = (b >> 2) & 1;
        int reg  = (b & 3) + ((b >> 3) << 2);
        base[reg * 64 + lane_lo + (q << 5)] = acc[b] + bias;
    }
}

// =====================================================================
// K_prep3: w_hh -> MFMA B-fragment shards for k_lstm2.
// wpk3[dir][js][nt(8)][kt(16)][lane(64)][j(8)] bf16; 524288 elts.
// =====================================================================
__global__ __launch_bounds__(256) void k_prep3(const float* __restrict__ whh_f,
                                               const float* __restrict__ whh_r,
                                               u16* __restrict__ wpk3) {
    const int gid  = blockIdx.x * 256 + threadIdx.x;    // [0, 524288)
    const int j    = gid & 7;
    const int lane = (gid >> 3) & 63;
    const int kt   = (gid >> 9) & 15;
    const int nt   = (gid >> 13) & 7;
    const int js   = (gid >> 16) & 3;
    const int dir  = (gid >> 18) & 1;
    const int n_local = nt * 32 + (lane & 31);
    const int jjl  = n_local >> 2;
    const int gate = n_local & 3;
    const int k    = kt * 16 + (lane >> 5) * 8 + j;
    const int row  = gate * 256 + js * 64 + jjl;
    const float* whh = dir ? whh_r : whh_f;
    wpk3[gid] = f2bf(whh[(size_t)row * 256 + k]);
}

// k_init: zero hxA (both parities, both dirs) and flags each launch
__global__ __launch_bounds__(256) void k_init(u32* __restrict__ hxA_u32,
                                              u32* __restrict__ flags) {
    const int i = blockIdx.x * 256 + threadIdx.x;
    if (i < 16384) hxA_u32[i] = 0u;          // 2*2*8192 u16 = 16384 u32
    if (i < 512)   flags[i]   = 0u;          // 2*64*4
}

// =====================================================================
// K3 v2: LSTM, weight-sharded across 8 blocks (2 dir x 4 js), MFMA.
// Block: 512 thr (8 waves). Wave w = n-tile (32 rows of n=jjl*4+gate).
// B-frags register-resident. h exchanged per step via global hxA (bf16,
// A-fragment order) with agent-scope fences + per-step flags.
// =====================================================================
__global__ __launch_bounds__(512) void k_lstm2(const u16* __restrict__ wpk3,
                                               const float* __restrict__ xgF,
                                               u16* __restrict__ hxA,
                                               u32* __restrict__ flags,
                                               float* __restrict__ hseq) {
    __shared__ float gbuf[32 * 276];          // [b][n_local 256], stride 276
    const int dir = blockIdx.x >> 2;
    const int js  = blockIdx.x & 3;
    const int tid = threadIdx.x;
    const int w   = tid >> 6;                 // n-tile 0..7
    const int l   = tid & 63;
    const int m   = l & 31;
    const int q   = l >> 5;

    // preload B fragments (16 kt x 4 VGPR)
    v8s Bf[16];
    {
        const u16* wb = wpk3 + ((((size_t)dir * 4 + js) * 8 + w) * 16) * 512 + (size_t)l * 8;
#pragma unroll
        for (int kt = 0; kt < 16; ++kt) Bf[kt] = *(const v8s*)(wb + kt * 512);
    }

    // epilogue cell ownership: b = tid&31, jjl = (tid>>5)*4 + c2
    const int eb  = tid & 31;
    const int ejb = tid >> 5;                 // 0..15
    float cst[4];
#pragma unroll
    for (int c2 = 0; c2 < 4; ++c2) cst[c2] = 0.0f;

    float* hout = hseq + (size_t)dir * 64 * 32 * 256;

    for (int s = 0; s < 64; ++s) {
        const int t = dir ? (63 - s) : s;
        // acc init from xgF (C-fragment layout)
        v16f acc;
        const float* xb = xgF + (((size_t)(dir * 64 + t) * 32) + js * 8 + w) * 1024 + l;
#pragma unroll
        for (int r = 0; r < 16; ++r) acc[r] = xb[r * 64];

        // wait for h_{s-1} from all 4 js blocks
        if (s > 0) {
            if (tid < 4) {
                u32 guard = 0;
                while (__hip_atomic_load(&flags[(dir * 64 + (s - 1)) * 4 + tid],
                                         __ATOMIC_ACQUIRE, __HIP_MEMORY_SCOPE_AGENT) == 0u) {
                    __builtin_amdgcn_s_sleep(2);
                    if (++guard > (1u << 27)) break;   // no-hang guard
                }
            }
            __syncthreads();
            __builtin_amdgcn_fence(__ATOMIC_ACQUIRE, "agent");
        }

        // h_{s-1} in buffer parity s&1 (zeros at s=0)
        const u16* hx = hxA + ((size_t)dir * 2 + (s & 1)) * 8192;
#pragma unroll
        for (int kt = 0; kt < 16; ++kt) {
            v8s af = *(const v8s*)(hx + ((kt * 2 + q) * 32 + m) * 8);
            acc = __builtin_amdgcn_mfma_f32_32x32x16_bf16(af, Bf[kt], acc, 0, 0, 0);
        }

        // gate preacts -> LDS (row = b, col = n_local)
#pragma unroll
        for (int r = 0; r < 16; ++r) {
            int row = (r & 3) + 8 * (r >> 2) + 4 * q;
            gbuf[row * 276 + w * 32 + m] = acc[r];
        }
        __syncthreads();

        // combine gates: thread owns (b=eb, jjl=ejb*4+c2); gates adjacent
        float hval[4];
        {
            const float* gb = &gbuf[eb * 276 + ejb * 16];
#pragma unroll
            for (int c2 = 0; c2 < 4; ++c2) {
                float4 gv = *(const float4*)(gb + c2 * 4);
                float i_ = sigf(gv.x), f_ = sigf(gv.y);
                float g_ = tanhfast(gv.z), o_ = sigf(gv.w);
                cst[c2] = f_ * cst[c2] + i_ * g_;
                hval[c2] = o_ * tanhfast(cst[c2]);
            }
        }
        // write h to hseq (fp32) and hxA parity (s+1)&1 (bf16 pairs)
        {
            float4 hv4 = make_float4(hval[0], hval[1], hval[2], hval[3]);
            *(float4*)&hout[((size_t)t * 32 + eb) * 256 + js * 64 + ejb * 4] = hv4;
            u16* hxn = hxA + ((size_t)dir * 2 + ((s + 1) & 1)) * 8192;
            const int kg0 = js * 64 + ejb * 4;
            u32 p0 = (u32)f2bf(hval[0]) | ((u32)f2bf(hval[1]) << 16);
            u32 p1 = (u32)f2bf(hval[2]) | ((u32)f2bf(hval[3]) << 16);
            u32* hxd = (u32*)hxn;
            hxd[((kg0 >> 3) * 32 + eb) * 4 + ((kg0 >> 1) & 3)]             = p0;
            hxd[(((kg0 + 2) >> 3) * 32 + eb) * 4 + (((kg0 + 2) >> 1) & 3)] = p1;
        }
        __syncthreads();                       // all stores issued (barrier drains vmcnt)
        if (tid == 0) {
            __builtin_amdgcn_fence(__ATOMIC_RELEASE, "agent");
            __hip_atomic_store(&flags[(dir * 64 + s) * 4 + js], 1u,
                               __ATOMIC_RELEASE, __HIP_MEMORY_SCOPE_AGENT);
        }
    }
}

// =====================================================================
// K4: head (unchanged)
// =====================================================================
__global__ __launch_bounds__(256) void k_head(const float* __restrict__ hseq,
                                              const float* __restrict__ hw,
                                              const float* __restrict__ hb,
                                              float* __restrict__ out) {
    const int id = blockIdx.x * 256 + threadIdx.x;
    const int o  = id & 31;
    const int u  = id >> 5;
    const int b  = u >> 6, t = u & 63;
    const float* pf = hseq + ((size_t)t * 32 + b) * 256;
    const float* pr = hseq + (size_t)64 * 32 * 256 + ((size_t)t * 32 + b) * 256;
    const float* wo = hw + (size_t)o * 512;
    float acc = hb[o];
    for (int j = 0; j < 256; j += 4) {
        float4 wa = *(const float4*)(wo + j);
        float4 wb = *(const float4*)(wo + 256 + j);
        float4 fa = *(const float4*)(pf + j);
        float4 fb = *(const float4*)(pr + j);
        acc = fmaf(wa.x, fa.x, acc); acc = fmaf(wa.y, fa.y, acc);
        acc = fmaf(wa.z, fa.z, acc); acc = fmaf(wa.w, fa.w, acc);
        acc = fmaf(wb.x, fb.x, acc); acc = fmaf(wb.y, fb.y, acc);
        acc = fmaf(wb.z, fb.z, acc); acc = fmaf(wb.w, fb.w, acc);
    }
    out[id] = sigf(acc);
}

// =====================================================================
extern "C" void kernel_launch(void* const* d_in, const int* in_sizes, int n_in,
                              void* d_out, int out_size, void* d_ws, size_t ws_size,
                              hipStream_t stream) {
    const int*   dlg   = (const int*)d_in[0];
    const float* emb   = (const float*)d_in[1];
    const float* w3    = (const float*)d_in[2];  const float* b3    = (const float*)d_in[3];
    const float* w4    = (const float*)d_in[4];  const float* b4    = (const float*)d_in[5];
    const float* w5    = (const float*)d_in[6];  const float* b5    = (const float*)d_in[7];
    const float* wih_f = (const float*)d_in[8];  const float* whh_f = (const float*)d_in[9];
    const float* bih_f = (const float*)d_in[10]; const float* bhh_f = (const float*)d_in[11];
    const float* wih_r = (const float*)d_in[12]; const float* whh_r = (const float*)d_in[13];
    const float* bih_r = (const float*)d_in[14]; const float* bhh_r = (const float*)d_in[15];
    const float* hw    = (const float*)d_in[16]; const float* hb    = (const float*)d_in[17];
    float* out = (float*)d_out;

    float* f     = (float*)d_ws;
    float* feat  = f;                         // 614400
    float* xgF   = f + 614400;                // 4194304
    float* hseq  = f + 4808704;               // 1048576
    u16*   wkr   = (u16*)(f + 5857280);       // 466944 u16
    u16*   wpk3  = (u16*)(f + 6090752);       // 524288 u16
    u16*   hxA   = (u16*)(f + 6352896);       // 32768 u16 (2 dir x 2 par x 8192)
    u32*   flags = (u32*)(f + 6369280);       // 512 u32
    // total ~25.5 MB

    hipLaunchKernelGGL(k_init, dim3(64), dim3(256), 0, stream,
                       (u32*)hxA, flags);
    hipLaunchKernelGGL(k_cprep, dim3(WKR_TOT / 256), dim3(256), 0, stream,
                       w3, w4, w5, wkr);
    hipLaunchKernelGGL(k_prep3, dim3(2048), dim3(256), 0, stream,
                       whh_f, whh_r, wpk3);
    hipLaunchKernelGGL(k_conv_mfma, dim3(1024), dim3(384), 0, stream,
                       dlg, emb, wkr, b3, b4, b5, feat);
    hipLaunchKernelGGL(k_xg, dim3(512), dim3(256), 0, stream,
                       feat, wih_f, bih_f, bhh_f, wih_r, bih_r, bhh_r, xgF);
    hipLaunchKernelGGL(k_lstm2, dim3(8), dim3(512), 0, stream,
                       wpk3, xgF, hxA, flags, hseq);
    hipLaunchKernelGGL(k_head, dim3(256), dim3(256), 0, stream,
                       hseq, hw, hb, out);
}